// Round 1
// baseline (6466.714 us; speedup 1.0000x reference)
//
#include <hip/hip_runtime.h>

typedef unsigned int u32;
typedef unsigned long long u64;

#define H_ 84
#define W_ 125
#define CIN 1024
#define CMID 512
#define NPOS 10500           // H_*W_
#define NA 94500             // NPOS*9
#define PRE 6000
#define POST 300
#define FMROW 128
#define FMSTRIDE 10752       // 84*128

// base anchor widths/heights (exact, derived from FEAT_STRIDE=16, scales 8/16/32, ratios .5/1/2)
__constant__ float c_aw[9] = {184.f, 368.f, 736.f, 128.f, 256.f, 512.f, 88.f, 176.f, 352.f};
__constant__ float c_ah[9] = { 96.f, 192.f, 384.f, 128.f, 256.f, 512.f, 176.f, 352.f, 704.f};

// ---------------- workspace layout (bytes) ----------------
#define OFF_FM      0ull                                   // 512*10752 f32 = 22,020,096
#define OFF_BOXES   22020096ull                            // 94500*4 f32   = 1,512,000
#define OFF_KEYSA   23532096ull                            // 94500 uint2   =   756,000
#define OFF_KEYSB   24288096ull                            //               =   756,000
#define OFF_PROPS   25044096ull                            // 6000 float4   =    96,000
#define OFF_AREAS   25140096ull                            // 6000 f32      =    24,000
#define OFF_VALIDW  25164096ull                            // 96 u64        =       768
#define OFF_MASK    25164864ull                            // 6000*96 u64   = 4,608,000
#define OFF_KEEPW   29772864ull                            // 96 u64        =       768
// total ~29.8 MB

// =====================================================================
// K1: 3x3 conv (1024->512) + bias + ReLU.  fp32, LDS-tiled.
// grid (16 ocb, 21 ytile), block 256. Tile: 32 OC x 4 rows x 125 cols.
// =====================================================================
__global__ __launch_bounds__(256) void k_conv3(const float* __restrict__ in,
                                               const float* __restrict__ w,
                                               const float* __restrict__ bias,
                                               float* __restrict__ fm) {
  __shared__ float Xs[8 * 6 * 136];   // [ic8][row6][col136]
  __shared__ float Ws[72 * 32];       // [e=ic*9+ky*3+kx][oc32]
  const int tid = threadIdx.x;
  const int tx = tid & 15;            // x group
  const int ty = tid >> 4;            // oc group
  const int ocb = blockIdx.x;         // 0..15
  const int y0 = blockIdx.y * 4;      // 0..80
  const int x0 = tx * 8;
  const int ocl = ty * 2;

  float acc[2][4][8];
#pragma unroll
  for (int o = 0; o < 2; ++o)
#pragma unroll
    for (int r = 0; r < 4; ++r)
#pragma unroll
      for (int xj = 0; xj < 8; ++xj) acc[o][r][xj] = 0.f;

#pragma unroll 1
  for (int icb = 0; icb < CIN; icb += 8) {
    __syncthreads();
    // stage input: 8 ic x 6 rows x 128 cols (col = x_in+1, zero-padded)
#pragma unroll
    for (int k = 0; k < 24; ++k) {
      int l = tid + k * 256;
      int col = l & 127;
      int rr = (l >> 7) % 6;
      int i8 = (l >> 7) / 6;
      int yi = y0 - 1 + rr;
      int xi = col - 1;
      float v = 0.f;
      if ((unsigned)yi < 84u && (unsigned)xi < 125u)
        v = in[(icb + i8) * (H_ * W_) + yi * W_ + xi];
      Xs[(i8 * 6 + rr) * 136 + col] = v;
    }
    // stage weights: 32 oc x 8 ic x 9 = 2304 floats (transposed to [e][oc])
#pragma unroll
    for (int q = 0; q < 9; ++q) {
      int idx = tid + q * 256;
      int oc = idx / 72;
      int e = idx % 72;
      Ws[e * 32 + oc] = w[(ocb * 32 + oc) * 9216 + icb * 9 + e];
    }
    __syncthreads();

#pragma unroll 1
    for (int i = 0; i < 8; ++i) {
      float xa[6][12];
#pragma unroll
      for (int r = 0; r < 6; ++r) {
#pragma unroll
        for (int m = 0; m < 3; ++m) {
          float4 tq = *(const float4*)&Xs[(i * 6 + r) * 136 + x0 + m * 4];
          xa[r][m * 4 + 0] = tq.x;
          xa[r][m * 4 + 1] = tq.y;
          xa[r][m * 4 + 2] = tq.z;
          xa[r][m * 4 + 3] = tq.w;
        }
      }
      float2 wv[9];
#pragma unroll
      for (int e9 = 0; e9 < 9; ++e9)
        wv[e9] = *(const float2*)&Ws[(i * 9 + e9) * 32 + ocl];
#pragma unroll
      for (int ky = 0; ky < 3; ++ky) {
#pragma unroll
        for (int kx = 0; kx < 3; ++kx) {
          float w0 = wv[ky * 3 + kx].x;
          float w1 = wv[ky * 3 + kx].y;
#pragma unroll
          for (int r = 0; r < 4; ++r) {
#pragma unroll
            for (int xj = 0; xj < 8; ++xj) {
              float xv = xa[r + ky][kx + xj];
              acc[0][r][xj] += w0 * xv;
              acc[1][r][xj] += w1 * xv;
            }
          }
        }
      }
    }
  }

  // epilogue: bias + relu + store (fm row stride 128 for alignment)
#pragma unroll
  for (int o = 0; o < 2; ++o) {
    int ocg = ocb * 32 + ocl + o;
    float b = bias[ocg];
#pragma unroll
    for (int r = 0; r < 4; ++r) {
      int y = y0 + r;
#pragma unroll
      for (int xj = 0; xj < 8; ++xj) {
        int x = x0 + xj;
        if (x < W_) {
          float v = acc[o][r][xj] + b;
          fm[ocg * FMSTRIDE + y * FMROW + x] = fmaxf(v, 0.f);
        }
      }
    }
  }
}

// =====================================================================
// K2: fused 1x1 heads + softmax + anchors + decode + clip + keys.
// grid 165 blocks x 64 threads (1 wave/block: LDS broadcast reads are the
// bottleneck and they cost per-wave-per-CU).
// =====================================================================
__global__ __launch_bounds__(64) void k_heads(const float* __restrict__ fm,
                                              const float* __restrict__ cls_w,
                                              const float* __restrict__ cls_b,
                                              const float* __restrict__ reg_w,
                                              const float* __restrict__ reg_b,
                                              const float* __restrict__ iminfo,
                                              float* __restrict__ out_bbox,
                                              float* __restrict__ out_cls,
                                              float* __restrict__ out_anch,
                                              float* __restrict__ boxes,
                                              uint2* __restrict__ keys) {
  __shared__ float wl[64 * 56];  // [ic64][o54 pad 56]
  const int tid = threadIdx.x;
  const int p = blockIdx.x * 64 + tid;
  const int pc = p < NPOS ? p : NPOS - 1;
  const int py = pc / W_;
  const int px = pc % W_;
  const int pos = py * FMROW + px;

  float acc[56];
#pragma unroll
  for (int o = 0; o < 56; ++o) acc[o] = 0.f;

#pragma unroll 1
  for (int icb = 0; icb < CMID; icb += 64) {
    __syncthreads();
    for (int l = tid; l < 64 * 54; l += 64) {
      int ic = l / 54;
      int o = l % 54;
      float wv = (o < 18) ? cls_w[o * CMID + icb + ic] : reg_w[(o - 18) * CMID + icb + ic];
      wl[ic * 56 + o] = wv;
    }
    __syncthreads();
#pragma unroll 4
    for (int i = 0; i < 64; ++i) {
      float v = fm[(icb + i) * FMSTRIDE + pos];
#pragma unroll
      for (int o4 = 0; o4 < 14; ++o4) {
        float4 w4 = *(const float4*)&wl[i * 56 + o4 * 4];
        acc[o4 * 4 + 0] += w4.x * v;
        acc[o4 * 4 + 1] += w4.y * v;
        acc[o4 * 4 + 2] += w4.z * v;
        acc[o4 * 4 + 3] += w4.w * v;
      }
    }
  }
  if (p >= NPOS) return;

  const float imh = iminfo[0];
  const float imw = iminfo[1];
  const float minsz = 16.0f * iminfo[2];

#pragma unroll
  for (int a = 0; a < 9; ++a) {
    const int n = p * 9 + a;
    float s0 = acc[a * 2 + 0] + cls_b[a * 2 + 0];
    float s1 = acc[a * 2 + 1] + cls_b[a * 2 + 1];
    out_cls[n * 2 + 0] = s0;
    out_cls[n * 2 + 1] = s1;

    float dx = acc[18 + a * 4 + 0] + reg_b[a * 4 + 0];
    float dy = acc[18 + a * 4 + 1] + reg_b[a * 4 + 1];
    float dw = acc[18 + a * 4 + 2] + reg_b[a * 4 + 2];
    float dh = acc[18 + a * 4 + 3] + reg_b[a * 4 + 3];
    out_bbox[n * 4 + 0] = dx;
    out_bbox[n * 4 + 1] = dy;
    out_bbox[n * 4 + 2] = dw;
    out_bbox[n * 4 + 3] = dh;

    float aw = c_aw[a], ah = c_ah[a];
    float cxs = px * 16.0f + 7.5f;
    float cys = py * 16.0f + 7.5f;
    float ax1 = cxs - 0.5f * (aw - 1.0f);
    float ay1 = cys - 0.5f * (ah - 1.0f);
    float ax2 = cxs + 0.5f * (aw - 1.0f);
    float ay2 = cys + 0.5f * (ah - 1.0f);
    out_anch[n * 4 + 0] = ax1;
    out_anch[n * 4 + 1] = ay1;
    out_anch[n * 4 + 2] = ax2;
    out_anch[n * 4 + 3] = ay2;

    // decode
    float wa = ax2 - ax1 + 1.0f;
    float ha = ay2 - ay1 + 1.0f;
    float cxa = ax1 + 0.5f * wa;
    float cya = ay1 + 0.5f * ha;
    float cx = dx * wa + cxa;
    float cy = dy * ha + cya;
    float ww = wa * expf(dw);
    float hh = ha * expf(dh);
    float bx1 = cx - 0.5f * ww;
    float by1 = cy - 0.5f * hh;
    float bx2 = cx + 0.5f * ww;
    float by2 = cy + 0.5f * hh;
    // clip
    bx1 = fminf(fmaxf(bx1, 0.f), imw - 1.f);
    by1 = fminf(fmaxf(by1, 0.f), imh - 1.f);
    bx2 = fminf(fmaxf(bx2, 0.f), imw - 1.f);
    by2 = fminf(fmaxf(by2, 0.f), imh - 1.f);
    boxes[n * 4 + 0] = bx1;
    boxes[n * 4 + 1] = by1;
    boxes[n * 4 + 2] = bx2;
    boxes[n * 4 + 3] = by2;

    bool valid = (bx2 - bx1 + 1.0f >= minsz) && (by2 - by1 + 1.0f >= minsz);
    float prob = 1.0f / (1.0f + expf(s0 - s1));  // softmax fg prob
    u32 key = valid ? __float_as_uint(prob) : 0u; // prob>0 -> key>0
    keys[n] = make_uint2(~key, (u32)n);           // ascending sort on ~key == descending score, stable
  }
}

// =====================================================================
// K3: single-block stable LSD radix sort (8 passes x 4 bits) of 94500
// (keyinv, idx) pairs.  Result: A = sorted ascending by keyinv.
// =====================================================================
__global__ __launch_bounds__(512) void k_sort(uint2* A, uint2* B) {
  __shared__ u32 hist[8192];  // [bin16][thread512], bin-major
  __shared__ u32 tot[512];
  const int t = threadIdx.x;
  const int s = t * 185;
  const int e = (s + 185 < NA) ? s + 185 : NA;

  uint2* src = A;
  uint2* dst = B;
#pragma unroll 1
  for (int pass = 0; pass < 8; ++pass) {
    const int sh = pass * 4;
#pragma unroll
    for (int k = 0; k < 16; ++k) hist[k * 512 + t] = 0;
    __syncthreads();
    for (int i = s; i < e; ++i) {
      u32 d = (src[i].x >> sh) & 15u;
      hist[d * 512 + t] += 1;
    }
    __syncthreads();
    // local exclusive scan of this thread's 16 contiguous flattened slots
    u32 run = 0;
#pragma unroll
    for (int j = 0; j < 16; ++j) {
      u32 v = hist[t * 16 + j];
      hist[t * 16 + j] = run;
      run += v;
    }
    tot[t] = run;
    __syncthreads();
    // Hillis-Steele inclusive scan of tot[512]
    for (int off = 1; off < 512; off <<= 1) {
      u32 add = (t >= off) ? tot[t - off] : 0u;
      __syncthreads();
      tot[t] += add;
      __syncthreads();
    }
    u32 cb = (t > 0) ? tot[t - 1] : 0u;
#pragma unroll
    for (int j = 0; j < 16; ++j) hist[t * 16 + j] += cb;
    __syncthreads();
    // stable scatter
    for (int i = s; i < e; ++i) {
      uint2 v = src[i];
      u32 d = (v.x >> sh) & 15u;
      u32 off = hist[d * 512 + t];
      hist[d * 512 + t] = off + 1;
      dst[off] = v;
    }
    __syncthreads();
    uint2* tmp = src;
    src = dst;
    dst = tmp;
  }
}

// =====================================================================
// K4: gather top-6000 props + areas + valid bitset (via wave ballot).
// =====================================================================
__global__ __launch_bounds__(256) void k_gather(const uint2* __restrict__ keys,
                                                const float4* __restrict__ boxes,
                                                float4* __restrict__ props,
                                                float* __restrict__ areas,
                                                u64* __restrict__ validw) {
  const int k = blockIdx.x * 256 + threadIdx.x;
  bool valid = false;
  if (k < PRE) {
    uint2 kv = keys[k];
    u32 key = ~kv.x;
    valid = key > 0u;
    float4 b = boxes[kv.y];
    props[k] = b;
    areas[k] = (b.z - b.x + 1.0f) * (b.w - b.y + 1.0f);
  }
  u64 bal = __ballot(valid);
  if ((threadIdx.x & 63) == 0 && k < PRE) validw[k >> 6] = bal;
}

// =====================================================================
// K5: IoU suppression bitmask. Row i, word w: bit b set iff
// j=w*64+b > i, j<6000, IoU(i,j) > 0.7.  Row stride 96 u64.
// =====================================================================
__global__ __launch_bounds__(256) void k_iou(const float4* __restrict__ props,
                                             const float* __restrict__ areas,
                                             u64* __restrict__ mask) {
  const int gid = blockIdx.x * 256 + threadIdx.x;
  const int i = gid / 94;
  const int w = gid - i * 94;
  if (i >= PRE) return;
  u64 bits = 0;
  const int j0 = w * 64;
  if (j0 + 63 > i) {
    float4 bi = props[i];
    float ai = areas[i];
    for (int b = 0; b < 64; ++b) {
      int j = j0 + b;
      if (j > i && j < PRE) {
        float4 bj = props[j];
        float iw = fminf(bi.z, bj.z) - fmaxf(bi.x, bj.x) + 1.0f;
        float ih = fminf(bi.w, bj.w) - fmaxf(bi.y, bj.y) + 1.0f;
        iw = fmaxf(iw, 0.f);
        ih = fmaxf(ih, 0.f);
        float inter = iw * ih;
        float aj = areas[j];
        if (inter > 0.7f * (ai + aj - inter)) bits |= (1ull << b);
      }
    }
  }
  mask[(u64)i * 96 + w] = bits;
}

// =====================================================================
// K6: sequential greedy NMS scan. ONE wave; suppressed bitset lives in
// registers (2 u64/lane); 16-deep register prefetch of mask rows.
// =====================================================================
__device__ __forceinline__ u64 bcast_u64(u64 v, int src) {
  u32 lo = (u32)v;
  u32 hi = (u32)(v >> 32);
  lo = (u32)__shfl((int)lo, src, 64);
  hi = (u32)__shfl((int)hi, src, 64);
  return ((u64)hi << 32) | (u64)lo;
}

__global__ __launch_bounds__(64) void k_nms(const u64* __restrict__ mask,
                                            const u64* __restrict__ validw,
                                            u64* __restrict__ keepw) {
  const int lane = threadIdx.x;
  const int w0 = (2 * lane < 96) ? 2 * lane : 0;
  const int w1 = (2 * lane < 96) ? 2 * lane + 1 : 1;
  u64 s0 = 0, s1 = 0;
  u64 b0[16], b1[16];
#pragma unroll
  for (int d = 0; d < 16; ++d) {
    b0[d] = mask[(u64)d * 96 + w0];
    b1[d] = mask[(u64)d * 96 + w1];
  }
#pragma unroll 1
  for (int i0 = 0; i0 < PRE; i0 += 16) {
#pragma unroll
    for (int d = 0; d < 16; ++d) {
      int i = i0 + d;
      int w = i >> 6;
      u64 cand = (w & 1) ? s1 : s0;
      u64 word = bcast_u64(cand, w >> 1);
      bool sup = (word >> (i & 63)) & 1ull;
      if (!sup) {
        s0 |= b0[d];
        s1 |= b1[d];
      }
      int ip = i + 16;
      if (ip > PRE - 1) ip = PRE - 1;
      b0[d] = mask[(u64)ip * 96 + w0];
      b1[d] = mask[(u64)ip * 96 + w1];
    }
  }
  if (2 * lane < 94) keepw[2 * lane] = ~s0 & validw[2 * lane];
  if (2 * lane + 1 < 94) keepw[2 * lane + 1] = ~s1 & validw[2 * lane + 1];
}

// =====================================================================
// K7: compact kept boxes in order into rois[300][4], zero-padded.
// =====================================================================
__global__ __launch_bounds__(128) void k_emit(const u64* __restrict__ keepw,
                                              const float4* __restrict__ props,
                                              float* __restrict__ rois) {
  __shared__ u32 base[94];
  const int t = threadIdx.x;
  for (int r = t; r < POST * 4; r += 128) rois[r] = 0.f;
  if (t < 94) base[t] = (u32)__popcll(keepw[t]);
  __syncthreads();
  if (t == 0) {
    u32 run = 0;
    for (int q = 0; q < 94; ++q) {
      u32 c = base[q];
      base[q] = run;
      run += c;
    }
  }
  __syncthreads();
  if (t < 94) {
    u64 kw = keepw[t];
    int rank = (int)base[t];
    while (kw) {
      int b = __ffsll((unsigned long long)kw) - 1;
      kw &= kw - 1;
      if (rank < POST) {
        float4 v = props[t * 64 + b];
        rois[rank * 4 + 0] = v.x;
        rois[rank * 4 + 1] = v.y;
        rois[rank * 4 + 2] = v.z;
        rois[rank * 4 + 3] = v.w;
      }
      rank++;
    }
  }
}

// =====================================================================
extern "C" void kernel_launch(void* const* d_in, const int* in_sizes, int n_in,
                              void* d_out, int out_size, void* d_ws, size_t ws_size,
                              hipStream_t stream) {
  const float* feat   = (const float*)d_in[0];
  const float* iminfo = (const float*)d_in[1];
  const float* conv_w = (const float*)d_in[2];
  const float* conv_b = (const float*)d_in[3];
  const float* cls_w  = (const float*)d_in[4];
  const float* cls_b  = (const float*)d_in[5];
  const float* reg_w  = (const float*)d_in[6];
  const float* reg_b  = (const float*)d_in[7];

  float* out = (float*)d_out;
  float* out_bbox = out;                 // 378000
  float* out_cls  = out + 378000;        // 189000
  float* out_rois = out + 567000;        // 1200
  float* out_anch = out + 568200;        // 378000

  char* ws = (char*)d_ws;
  float* fm      = (float*)(ws + OFF_FM);
  float* boxes   = (float*)(ws + OFF_BOXES);
  uint2* keysA   = (uint2*)(ws + OFF_KEYSA);
  uint2* keysB   = (uint2*)(ws + OFF_KEYSB);
  float4* props  = (float4*)(ws + OFF_PROPS);
  float* areas   = (float*)(ws + OFF_AREAS);
  u64* validw    = (u64*)(ws + OFF_VALIDW);
  u64* mask      = (u64*)(ws + OFF_MASK);
  u64* keepw     = (u64*)(ws + OFF_KEEPW);

  k_conv3<<<dim3(16, 21), 256, 0, stream>>>(feat, conv_w, conv_b, fm);
  k_heads<<<165, 64, 0, stream>>>(fm, cls_w, cls_b, reg_w, reg_b, iminfo,
                                  out_bbox, out_cls, out_anch, boxes, keysA);
  k_sort<<<1, 512, 0, stream>>>(keysA, keysB);
  k_gather<<<24, 256, 0, stream>>>(keysA, (const float4*)boxes, props, areas, validw);
  k_iou<<<2204, 256, 0, stream>>>(props, areas, mask);
  k_nms<<<1, 64, 0, stream>>>(mask, validw, keepw);
  k_emit<<<1, 128, 0, stream>>>(keepw, props, out_rois);
}

// Round 2
// 4101.504 us; speedup vs baseline: 1.5767x; 1.5767x over previous
//
#include <hip/hip_runtime.h>

typedef unsigned int u32;
typedef unsigned long long u64;

#define H_ 84
#define W_ 125
#define CIN 1024
#define CMID 512
#define NPOS 10500           // H_*W_
#define NA 94500             // NPOS*9
#define PRE 6000
#define POST 300
#define FMROW 128
#define FMSTRIDE 10752       // 84*128
#define SELCAP 16384

// base anchor widths/heights (exact)
__constant__ float c_aw[9] = {184.f, 368.f, 736.f, 128.f, 256.f, 512.f, 88.f, 176.f, 352.f};
__constant__ float c_ah[9] = { 96.f, 192.f, 384.f, 128.f, 256.f, 512.f, 176.f, 352.f, 704.f};

// ---------------- workspace layout (bytes) ----------------
#define OFF_FM      0ull            // 512*10752 f32 = 22,020,096
#define OFF_BOXES   22020096ull     // 94500*4 f32   = 1,512,000
#define OFF_KEYS    23532096ull     // 94500 uint2   =   756,000
#define OFF_SELA    24288096ull     // 16384 uint2   =   131,072
#define OFF_SELB    24419168ull     // 16384 uint2   =   131,072
#define OFF_PROPS   24550240ull     // 6000 float4   =    96,000
#define OFF_AREAS   24646240ull     // 6000 f32      =    24,000
#define OFF_VALIDW  24670240ull     // 96 u64        =       768
#define OFF_MASK    24671008ull     // 6000*96 u64   = 4,608,000
#define OFF_KEEPW   29279008ull     // 96 u64        =       768
// total ~29.3 MB

// =====================================================================
// K1: 3x3 conv (1024->512) + bias + ReLU.  fp32.
// Tile: 32 OC x 2 rows x 64 cols. Block 128 thr (tx=tid&7: 8 cols each;
// ty=tid>>3: 2 oc each). Grid (16 ocb, 42 ytile, 2 xtile) = 1344 blocks.
// Bank-conflict-free: Xs float4 reads 2-way aliased (free), Ws broadcast.
// =====================================================================
__global__ __launch_bounds__(128) void k_conv3(const float* __restrict__ in,
                                               const float* __restrict__ w,
                                               const float* __restrict__ bias,
                                               float* __restrict__ fm) {
  __shared__ float Xs[8 * 4 * 72];   // [ic8][row4][col72]  9.2 KB
  __shared__ float Ws[72 * 32];      // [e=ic*9+ky*3+kx][oc32] 9.2 KB
  const int tid = threadIdx.x;
  const int tx = tid & 7;            // 8 col-groups of 8
  const int ty = tid >> 3;           // 0..15, 2 oc each
  const int ocb = blockIdx.x;        // 0..15
  const int y0 = blockIdx.y * 2;     // 0..82
  const int x0g = blockIdx.z * 64;   // 0, 64
  const int xb = tx * 8;

  float acc[2][2][8];
#pragma unroll
  for (int o = 0; o < 2; ++o)
#pragma unroll
    for (int r = 0; r < 2; ++r)
#pragma unroll
      for (int xj = 0; xj < 8; ++xj) acc[o][r][xj] = 0.f;

#pragma unroll 1
  for (int icb = 0; icb < CIN; icb += 8) {
    __syncthreads();
    // stage input: 8 ic x 4 rows x 72 cols (col c = input col x0g-1+c)
#pragma unroll
    for (int k = 0; k < 18; ++k) {
      int l = tid + k * 128;
      int i8 = l / 288;
      int rem = l - i8 * 288;
      int rr = rem / 72;
      int c = rem - rr * 72;
      int yi = y0 - 1 + rr;
      int xi = x0g - 1 + c;
      float v = 0.f;
      if ((unsigned)yi < 84u && (unsigned)xi < 125u)
        v = in[(icb + i8) * (H_ * W_) + yi * W_ + xi];
      Xs[(i8 * 4 + rr) * 72 + c] = v;
    }
    // stage weights: 32 oc x 8 ic x 9 (transposed to [e][oc])
#pragma unroll
    for (int k = 0; k < 18; ++k) {
      int l = tid + k * 128;
      int oc = l / 72;
      int e = l - oc * 72;
      Ws[e * 32 + oc] = w[(ocb * 32 + oc) * 9216 + icb * 9 + e];
    }
    __syncthreads();

#pragma unroll 1
    for (int i = 0; i < 8; ++i) {
      float2 wv[9];
#pragma unroll
      for (int e9 = 0; e9 < 9; ++e9)
        wv[e9] = *(const float2*)&Ws[(i * 9 + e9) * 32 + ty * 2];
#pragma unroll
      for (int rr = 0; rr < 4; ++rr) {
        float xr[12];
#pragma unroll
        for (int m = 0; m < 3; ++m) {
          float4 tq = *(const float4*)&Xs[(i * 4 + rr) * 72 + xb + m * 4];
          xr[m * 4 + 0] = tq.x;
          xr[m * 4 + 1] = tq.y;
          xr[m * 4 + 2] = tq.z;
          xr[m * 4 + 3] = tq.w;
        }
#pragma unroll
        for (int ky = 0; ky < 3; ++ky) {
          int ro = rr - ky;
          if (ro >= 0 && ro < 2) {
#pragma unroll
            for (int kx = 0; kx < 3; ++kx) {
              float2 w2 = wv[ky * 3 + kx];
#pragma unroll
              for (int xj = 0; xj < 8; ++xj) {
                float xv = xr[xj + kx];
                acc[0][ro][xj] += w2.x * xv;
                acc[1][ro][xj] += w2.y * xv;
              }
            }
          }
        }
      }
    }
  }

  // epilogue: bias + relu + float4 stores (fm row stride 128; pad cols ok)
#pragma unroll
  for (int o = 0; o < 2; ++o) {
    int ocg = ocb * 32 + ty * 2 + o;
    float b = bias[ocg];
#pragma unroll
    for (int r = 0; r < 2; ++r) {
      int y = y0 + r;
      float4 v0, v1;
      v0.x = fmaxf(acc[o][r][0] + b, 0.f);
      v0.y = fmaxf(acc[o][r][1] + b, 0.f);
      v0.z = fmaxf(acc[o][r][2] + b, 0.f);
      v0.w = fmaxf(acc[o][r][3] + b, 0.f);
      v1.x = fmaxf(acc[o][r][4] + b, 0.f);
      v1.y = fmaxf(acc[o][r][5] + b, 0.f);
      v1.z = fmaxf(acc[o][r][6] + b, 0.f);
      v1.w = fmaxf(acc[o][r][7] + b, 0.f);
      float* p = &fm[ocg * FMSTRIDE + y * FMROW + x0g + xb];
      *(float4*)p = v0;
      *(float4*)(p + 4) = v1;
    }
  }
}

// =====================================================================
// K2: fused 1x1 heads + softmax + anchors + decode + clip + keys.
// =====================================================================
__global__ __launch_bounds__(64) void k_heads(const float* __restrict__ fm,
                                              const float* __restrict__ cls_w,
                                              const float* __restrict__ cls_b,
                                              const float* __restrict__ reg_w,
                                              const float* __restrict__ reg_b,
                                              const float* __restrict__ iminfo,
                                              float* __restrict__ out_bbox,
                                              float* __restrict__ out_cls,
                                              float* __restrict__ out_anch,
                                              float* __restrict__ boxes,
                                              uint2* __restrict__ keys) {
  __shared__ float wl[64 * 56];  // [ic64][o54 pad 56]
  const int tid = threadIdx.x;
  const int p = blockIdx.x * 64 + tid;
  const int pc = p < NPOS ? p : NPOS - 1;
  const int py = pc / W_;
  const int px = pc % W_;
  const int pos = py * FMROW + px;

  float acc[56];
#pragma unroll
  for (int o = 0; o < 56; ++o) acc[o] = 0.f;

#pragma unroll 1
  for (int icb = 0; icb < CMID; icb += 64) {
    __syncthreads();
    for (int l = tid; l < 64 * 54; l += 64) {
      int ic = l / 54;
      int o = l % 54;
      float wv = (o < 18) ? cls_w[o * CMID + icb + ic] : reg_w[(o - 18) * CMID + icb + ic];
      wl[ic * 56 + o] = wv;
    }
    __syncthreads();
#pragma unroll 4
    for (int i = 0; i < 64; ++i) {
      float v = fm[(icb + i) * FMSTRIDE + pos];
#pragma unroll
      for (int o4 = 0; o4 < 14; ++o4) {
        float4 w4 = *(const float4*)&wl[i * 56 + o4 * 4];
        acc[o4 * 4 + 0] += w4.x * v;
        acc[o4 * 4 + 1] += w4.y * v;
        acc[o4 * 4 + 2] += w4.z * v;
        acc[o4 * 4 + 3] += w4.w * v;
      }
    }
  }
  if (p >= NPOS) return;

  const float imh = iminfo[0];
  const float imw = iminfo[1];
  const float minsz = 16.0f * iminfo[2];

#pragma unroll
  for (int a = 0; a < 9; ++a) {
    const int n = p * 9 + a;
    float s0 = acc[a * 2 + 0] + cls_b[a * 2 + 0];
    float s1 = acc[a * 2 + 1] + cls_b[a * 2 + 1];
    out_cls[n * 2 + 0] = s0;
    out_cls[n * 2 + 1] = s1;

    float dx = acc[18 + a * 4 + 0] + reg_b[a * 4 + 0];
    float dy = acc[18 + a * 4 + 1] + reg_b[a * 4 + 1];
    float dw = acc[18 + a * 4 + 2] + reg_b[a * 4 + 2];
    float dh = acc[18 + a * 4 + 3] + reg_b[a * 4 + 3];
    out_bbox[n * 4 + 0] = dx;
    out_bbox[n * 4 + 1] = dy;
    out_bbox[n * 4 + 2] = dw;
    out_bbox[n * 4 + 3] = dh;

    float aw = c_aw[a], ah = c_ah[a];
    float cxs = px * 16.0f + 7.5f;
    float cys = py * 16.0f + 7.5f;
    float ax1 = cxs - 0.5f * (aw - 1.0f);
    float ay1 = cys - 0.5f * (ah - 1.0f);
    float ax2 = cxs + 0.5f * (aw - 1.0f);
    float ay2 = cys + 0.5f * (ah - 1.0f);
    out_anch[n * 4 + 0] = ax1;
    out_anch[n * 4 + 1] = ay1;
    out_anch[n * 4 + 2] = ax2;
    out_anch[n * 4 + 3] = ay2;

    float wa = ax2 - ax1 + 1.0f;
    float ha = ay2 - ay1 + 1.0f;
    float cxa = ax1 + 0.5f * wa;
    float cya = ay1 + 0.5f * ha;
    float cx = dx * wa + cxa;
    float cy = dy * ha + cya;
    float ww = wa * expf(dw);
    float hh = ha * expf(dh);
    float bx1 = cx - 0.5f * ww;
    float by1 = cy - 0.5f * hh;
    float bx2 = cx + 0.5f * ww;
    float by2 = cy + 0.5f * hh;
    bx1 = fminf(fmaxf(bx1, 0.f), imw - 1.f);
    by1 = fminf(fmaxf(by1, 0.f), imh - 1.f);
    bx2 = fminf(fmaxf(bx2, 0.f), imw - 1.f);
    by2 = fminf(fmaxf(by2, 0.f), imh - 1.f);
    boxes[n * 4 + 0] = bx1;
    boxes[n * 4 + 1] = by1;
    boxes[n * 4 + 2] = bx2;
    boxes[n * 4 + 3] = by2;

    bool valid = (bx2 - bx1 + 1.0f >= minsz) && (by2 - by1 + 1.0f >= minsz);
    float prob = 1.0f / (1.0f + expf(s0 - s1));
    u32 key = valid ? __float_as_uint(prob) : 0u;
    keys[n] = make_uint2(~key, (u32)n);  // ascending on ~key == descending score, stable
  }
}

// =====================================================================
// K3: single-block select + small sort.
// Two-level 12-bit histograms find the 6000th-smallest keyinv threshold;
// stable compaction of selected (~6000+eps) pairs; 8-pass LSD radix on
// the selected set only. Result: selA[0..5999] = top-6000 in order.
// =====================================================================
__global__ __launch_bounds__(512) void k_select(const uint2* __restrict__ keys,
                                                uint2* __restrict__ selA,
                                                uint2* __restrict__ selB) {
  __shared__ u32 h[8192];    // L1/L2 hist use [0..4096); radix uses [16][512]
  __shared__ u32 stot[512];
  __shared__ u32 sB1, sLt1, sB2, sN;
  const int t = threadIdx.x;
  const int s = t * 185;
  const int e = (s + 185 < NA) ? s + 185 : NA;

  // ---- L1 hist: top 12 bits ----
  for (int i = t; i < 4096; i += 512) h[i] = 0;
  __syncthreads();
  for (int i = s; i < e; ++i) atomicAdd(&h[keys[i].x >> 20], 1u);
  __syncthreads();
  {
    u32 loc = 0;
#pragma unroll
    for (int j = 0; j < 8; ++j) loc += h[t * 8 + j];
    stot[t] = loc;
    __syncthreads();
    for (int off = 1; off < 512; off <<= 1) {
      u32 add = (t >= off) ? stot[t - off] : 0u;
      __syncthreads();
      stot[t] += add;
      __syncthreads();
    }
    u32 cb = stot[t] - loc;
    if (cb < PRE && stot[t] >= PRE) {
      u32 run = cb;
#pragma unroll
      for (int j = 0; j < 8; ++j) {
        u32 c = h[t * 8 + j];
        if (run < PRE && run + c >= PRE) { sB1 = t * 8 + j; sLt1 = run; }
        run += c;
      }
    }
  }
  __syncthreads();
  const u32 B1 = sB1;
  const u32 T2 = PRE - sLt1;  // >= 1

  // ---- L2 hist: bits 8..19 within bin B1 ----
  for (int i = t; i < 4096; i += 512) h[i] = 0;
  __syncthreads();
  for (int i = s; i < e; ++i) {
    u32 k = keys[i].x;
    if ((k >> 20) == B1) atomicAdd(&h[(k >> 8) & 0xFFFu], 1u);
  }
  __syncthreads();
  {
    u32 loc = 0;
#pragma unroll
    for (int j = 0; j < 8; ++j) loc += h[t * 8 + j];
    stot[t] = loc;
    __syncthreads();
    for (int off = 1; off < 512; off <<= 1) {
      u32 add = (t >= off) ? stot[t - off] : 0u;
      __syncthreads();
      stot[t] += add;
      __syncthreads();
    }
    u32 cb = stot[t] - loc;
    if (cb < T2 && stot[t] >= T2) {
      u32 run = cb;
#pragma unroll
      for (int j = 0; j < 8; ++j) {
        u32 c = h[t * 8 + j];
        if (run < T2 && run + c >= T2) { sB2 = t * 8 + j; }
        run += c;
      }
    }
  }
  __syncthreads();
  const u32 B2 = sB2;

  // ---- stable compaction of pred(key): prefix-closed threshold ----
  u32 cnt = 0;
  for (int i = s; i < e; ++i) {
    u32 k = keys[i].x;
    u32 hi = k >> 20;
    if (hi < B1 || (hi == B1 && ((k >> 8) & 0xFFFu) <= B2)) cnt++;
  }
  stot[t] = cnt;
  __syncthreads();
  for (int off = 1; off < 512; off <<= 1) {
    u32 add = (t >= off) ? stot[t - off] : 0u;
    __syncthreads();
    stot[t] += add;
    __syncthreads();
  }
  u32 base = stot[t] - cnt;
  if (t == 511) sN = stot[511] < SELCAP ? stot[511] : SELCAP;
  for (int i = s; i < e; ++i) {
    uint2 v = keys[i];
    u32 hi = v.x >> 20;
    if (hi < B1 || (hi == B1 && ((v.x >> 8) & 0xFFFu) <= B2)) {
      if (base < SELCAP) selA[base] = v;
      base++;
    }
  }
  __syncthreads();
  const int n = (int)sN;  // >= 6000 by construction

  // ---- 8-pass LSD radix on selected set ----
  const int q = (n + 511) / 512;
  const int s2 = t * q;
  const int e2 = (s2 + q < n) ? s2 + q : n;
  uint2* src = selA;
  uint2* dst = selB;
#pragma unroll 1
  for (int pass = 0; pass < 8; ++pass) {
    const int sh = pass * 4;
#pragma unroll
    for (int k = 0; k < 16; ++k) h[k * 512 + t] = 0;
    __syncthreads();
    for (int i = s2; i < e2; ++i) {
      u32 d = (src[i].x >> sh) & 15u;
      h[d * 512 + t] += 1;
    }
    __syncthreads();
    u32 run = 0;
#pragma unroll
    for (int j = 0; j < 16; ++j) {
      u32 v = h[t * 16 + j];
      h[t * 16 + j] = run;
      run += v;
    }
    stot[t] = run;
    __syncthreads();
    for (int off = 1; off < 512; off <<= 1) {
      u32 add = (t >= off) ? stot[t - off] : 0u;
      __syncthreads();
      stot[t] += add;
      __syncthreads();
    }
    u32 cb = (t > 0) ? stot[t - 1] : 0u;
#pragma unroll
    for (int j = 0; j < 16; ++j) h[t * 16 + j] += cb;
    __syncthreads();
    for (int i = s2; i < e2; ++i) {
      uint2 v = src[i];
      u32 d = (v.x >> sh) & 15u;
      u32 off = h[d * 512 + t];
      h[d * 512 + t] = off + 1;
      dst[off] = v;
    }
    __syncthreads();
    uint2* tmp = src;
    src = dst;
    dst = tmp;
  }
  // 8 passes (even) -> sorted result in selA
}

// =====================================================================
// K4: gather top-6000 props + areas + valid bitset.
// =====================================================================
__global__ __launch_bounds__(256) void k_gather(const uint2* __restrict__ sel,
                                                const float4* __restrict__ boxes,
                                                float4* __restrict__ props,
                                                float* __restrict__ areas,
                                                u64* __restrict__ validw) {
  const int k = blockIdx.x * 256 + threadIdx.x;
  bool valid = false;
  if (k < PRE) {
    uint2 kv = sel[k];
    u32 key = ~kv.x;
    valid = key > 0u;
    float4 b = boxes[kv.y];
    props[k] = b;
    areas[k] = (b.z - b.x + 1.0f) * (b.w - b.y + 1.0f);
  }
  u64 bal = __ballot(valid);
  if ((threadIdx.x & 63) == 0 && k < PRE) validw[k >> 6] = bal;
}

// =====================================================================
// K5: IoU suppression bitmask.
// =====================================================================
__global__ __launch_bounds__(256) void k_iou(const float4* __restrict__ props,
                                             const float* __restrict__ areas,
                                             u64* __restrict__ mask) {
  const int gid = blockIdx.x * 256 + threadIdx.x;
  const int i = gid / 94;
  const int w = gid - i * 94;
  if (i >= PRE) return;
  u64 bits = 0;
  const int j0 = w * 64;
  if (j0 + 63 > i) {
    float4 bi = props[i];
    float ai = areas[i];
    for (int b = 0; b < 64; ++b) {
      int j = j0 + b;
      if (j > i && j < PRE) {
        float4 bj = props[j];
        float iw = fminf(bi.z, bj.z) - fmaxf(bi.x, bj.x) + 1.0f;
        float ih = fminf(bi.w, bj.w) - fmaxf(bi.y, bj.y) + 1.0f;
        iw = fmaxf(iw, 0.f);
        ih = fmaxf(ih, 0.f);
        float inter = iw * ih;
        float aj = areas[j];
        if (inter > 0.7f * (ai + aj - inter)) bits |= (1ull << b);
      }
    }
  }
  mask[(u64)i * 96 + w] = bits;
}

// =====================================================================
// K6: sequential greedy NMS scan (one wave, registers + shfl).
// =====================================================================
__device__ __forceinline__ u64 bcast_u64(u64 v, int src) {
  u32 lo = (u32)v;
  u32 hi = (u32)(v >> 32);
  lo = (u32)__shfl((int)lo, src, 64);
  hi = (u32)__shfl((int)hi, src, 64);
  return ((u64)hi << 32) | (u64)lo;
}

__global__ __launch_bounds__(64) void k_nms(const u64* __restrict__ mask,
                                            const u64* __restrict__ validw,
                                            u64* __restrict__ keepw) {
  const int lane = threadIdx.x;
  const int w0 = (2 * lane < 96) ? 2 * lane : 0;
  const int w1 = (2 * lane < 96) ? 2 * lane + 1 : 1;
  u64 s0 = 0, s1 = 0;
  u64 b0[16], b1[16];
#pragma unroll
  for (int d = 0; d < 16; ++d) {
    b0[d] = mask[(u64)d * 96 + w0];
    b1[d] = mask[(u64)d * 96 + w1];
  }
#pragma unroll 1
  for (int i0 = 0; i0 < PRE; i0 += 16) {
#pragma unroll
    for (int d = 0; d < 16; ++d) {
      int i = i0 + d;
      int w = i >> 6;
      u64 cand = (w & 1) ? s1 : s0;
      u64 word = bcast_u64(cand, w >> 1);
      bool sup = (word >> (i & 63)) & 1ull;
      if (!sup) {
        s0 |= b0[d];
        s1 |= b1[d];
      }
      int ip = i + 16;
      if (ip > PRE - 1) ip = PRE - 1;
      b0[d] = mask[(u64)ip * 96 + w0];
      b1[d] = mask[(u64)ip * 96 + w1];
    }
  }
  if (2 * lane < 94) keepw[2 * lane] = ~s0 & validw[2 * lane];
  if (2 * lane + 1 < 94) keepw[2 * lane + 1] = ~s1 & validw[2 * lane + 1];
}

// =====================================================================
// K7: compact kept boxes in order into rois[300][4], zero-padded.
// =====================================================================
__global__ __launch_bounds__(128) void k_emit(const u64* __restrict__ keepw,
                                              const float4* __restrict__ props,
                                              float* __restrict__ rois) {
  __shared__ u32 base[94];
  const int t = threadIdx.x;
  for (int r = t; r < POST * 4; r += 128) rois[r] = 0.f;
  if (t < 94) base[t] = (u32)__popcll(keepw[t]);
  __syncthreads();
  if (t == 0) {
    u32 run = 0;
    for (int q = 0; q < 94; ++q) {
      u32 c = base[q];
      base[q] = run;
      run += c;
    }
  }
  __syncthreads();
  if (t < 94) {
    u64 kw = keepw[t];
    int rank = (int)base[t];
    while (kw) {
      int b = __ffsll((unsigned long long)kw) - 1;
      kw &= kw - 1;
      if (rank < POST) {
        float4 v = props[t * 64 + b];
        rois[rank * 4 + 0] = v.x;
        rois[rank * 4 + 1] = v.y;
        rois[rank * 4 + 2] = v.z;
        rois[rank * 4 + 3] = v.w;
      }
      rank++;
    }
  }
}

// =====================================================================
extern "C" void kernel_launch(void* const* d_in, const int* in_sizes, int n_in,
                              void* d_out, int out_size, void* d_ws, size_t ws_size,
                              hipStream_t stream) {
  const float* feat   = (const float*)d_in[0];
  const float* iminfo = (const float*)d_in[1];
  const float* conv_w = (const float*)d_in[2];
  const float* conv_b = (const float*)d_in[3];
  const float* cls_w  = (const float*)d_in[4];
  const float* cls_b  = (const float*)d_in[5];
  const float* reg_w  = (const float*)d_in[6];
  const float* reg_b  = (const float*)d_in[7];

  float* out = (float*)d_out;
  float* out_bbox = out;                 // 378000
  float* out_cls  = out + 378000;        // 189000
  float* out_rois = out + 567000;        // 1200
  float* out_anch = out + 568200;        // 378000

  char* ws = (char*)d_ws;
  float* fm      = (float*)(ws + OFF_FM);
  float* boxes   = (float*)(ws + OFF_BOXES);
  uint2* keysA   = (uint2*)(ws + OFF_KEYS);
  uint2* selA    = (uint2*)(ws + OFF_SELA);
  uint2* selB    = (uint2*)(ws + OFF_SELB);
  float4* props  = (float4*)(ws + OFF_PROPS);
  float* areas   = (float*)(ws + OFF_AREAS);
  u64* validw    = (u64*)(ws + OFF_VALIDW);
  u64* mask      = (u64*)(ws + OFF_MASK);
  u64* keepw     = (u64*)(ws + OFF_KEEPW);

  k_conv3<<<dim3(16, 42, 2), 128, 0, stream>>>(feat, conv_w, conv_b, fm);
  k_heads<<<165, 64, 0, stream>>>(fm, cls_w, cls_b, reg_w, reg_b, iminfo,
                                  out_bbox, out_cls, out_anch, boxes, keysA);
  k_select<<<1, 512, 0, stream>>>(keysA, selA, selB);
  k_gather<<<24, 256, 0, stream>>>(selA, (const float4*)boxes, props, areas, validw);
  k_iou<<<2204, 256, 0, stream>>>(props, areas, mask);
  k_nms<<<1, 64, 0, stream>>>(mask, validw, keepw);
  k_emit<<<1, 128, 0, stream>>>(keepw, props, out_rois);
}

// Round 3
// 3108.300 us; speedup vs baseline: 2.0805x; 1.3195x over previous
//
#include <hip/hip_runtime.h>

typedef unsigned int u32;
typedef unsigned long long u64;

#define H_ 84
#define W_ 125
#define CIN 1024
#define CMID 512
#define NPOS 10500           // H_*W_
#define NA 94500             // NPOS*9
#define PRE 6000
#define POST 300
#define FMROW 128
#define FMSTRIDE 10752       // 84*128
#define SELCAP 16384

// base anchor widths/heights (exact)
__constant__ float c_aw[9] = {184.f, 368.f, 736.f, 128.f, 256.f, 512.f, 88.f, 176.f, 352.f};
__constant__ float c_ah[9] = { 96.f, 192.f, 384.f, 128.f, 256.f, 512.f, 176.f, 352.f, 704.f};

// ---------------- workspace layout (bytes) ----------------
#define OFF_FM      0ull            // 512*10752 f32 = 22,020,096
#define OFF_BOXES   22020096ull     // 94500*4 f32   = 1,512,000
#define OFF_KEYS    23532096ull     // 94500 uint2   =   756,000
#define OFF_SELA    24288096ull     // 16384 uint2   =   131,072
#define OFF_SELB    24419168ull     // 16384 uint2   =   131,072
#define OFF_PROPS   24550240ull     // 6000 float4   =    96,000
#define OFF_AREAS   24646240ull     // 6000 f32      =    24,000
#define OFF_VALIDW  24670240ull     // 96 u64        =       768
#define OFF_MASK    24671008ull     // 6000*96 u64   = 4,608,000
#define OFF_KEEPW   29279008ull     // 96 u64        =       768
// total ~29.3 MB

// =====================================================================
// K1: 3x3 conv (1024->512) + bias + ReLU.  fp32, scalar-cache weights.
// Block 256 thr = 4 waves. Wave wv handles oc0 = ocb*16 + wv*4 (4 oc,
// wave-uniform -> weights via s_load into SGPRs, zero LDS/VGPR cost).
// Lane covers out px {2l, 2l+1} across full row width; tile = 16 oc x
// 2 rows x 125 cols. Grid (32 ocb, 42 y) = 1344 blocks. LDS holds only
// the input slab Xs[16ic][4rows][132cols] (33.8 KB), staged linearly
// (conflict-free writes); reads are 8B-aligned float2 (2-way = free).
// =====================================================================
__global__ __launch_bounds__(256, 4) void k_conv3(const float* __restrict__ in,
                                                  const float* __restrict__ w,
                                                  const float* __restrict__ bias,
                                                  float* __restrict__ fm) {
  __shared__ float Xs[16 * 4 * 132];   // 33,792 B
  const int tid = threadIdx.x;
  const int lane = tid & 63;
  const int wvi = __builtin_amdgcn_readfirstlane(tid >> 6);  // 0..3 wave-uniform
  const int ocb = blockIdx.x;          // 0..31
  const int y0 = blockIdx.y * 2;       // 0..82
  const int oc0 = ocb * 16 + wvi * 4;

  float acc[4][2][2];
#pragma unroll
  for (int o = 0; o < 4; ++o)
#pragma unroll
    for (int r = 0; r < 2; ++r) {
      acc[o][r][0] = 0.f;
      acc[o][r][1] = 0.f;
    }

  const int cb = 2 * lane;             // Xs col base (covers cols cb..cb+3)

#pragma unroll 1
  for (int icb = 0; icb < CIN; icb += 16) {
    __syncthreads();
    // stage input: 16 ic x 4 rows x 132 cols, linear writes (no conflicts)
#pragma unroll
    for (int k = 0; k < 33; ++k) {
      int l = tid + k * 256;
      int r132 = l / 132;              // 0..63
      int c = l - r132 * 132;
      int i = r132 >> 2;
      int rr = r132 & 3;
      int yi = y0 - 1 + rr;
      int xi = c - 1;
      float v = 0.f;
      if ((unsigned)yi < 84u && (unsigned)xi < 125u)
        v = in[(icb + i) * (H_ * W_) + yi * W_ + xi];
      Xs[l] = v;
    }
    __syncthreads();

#pragma unroll 2
    for (int i = 0; i < 16; ++i) {
      const int ic = icb + i;
      // wave-uniform weights -> SGPRs (compiler emits s_load)
      float ws[4][9];
#pragma unroll
      for (int o = 0; o < 4; ++o)
#pragma unroll
        for (int e = 0; e < 9; ++e)
          ws[o][e] = w[(oc0 + o) * 9216 + ic * 9 + e];

      // input: 4 rows x 4 cols per lane, two aligned float2 per row
      float x4[4][4];
#pragma unroll
      for (int rr = 0; rr < 4; ++rr) {
        float2 lo = *(const float2*)&Xs[(i * 4 + rr) * 132 + cb];
        float2 hi = *(const float2*)&Xs[(i * 4 + rr) * 132 + cb + 2];
        x4[rr][0] = lo.x;
        x4[rr][1] = lo.y;
        x4[rr][2] = hi.x;
        x4[rr][3] = hi.y;
      }

#pragma unroll
      for (int o = 0; o < 4; ++o)
#pragma unroll
        for (int r = 0; r < 2; ++r)
#pragma unroll
          for (int ky = 0; ky < 3; ++ky)
#pragma unroll
            for (int kx = 0; kx < 3; ++kx) {
              float wv2 = ws[o][ky * 3 + kx];
              acc[o][r][0] += wv2 * x4[r + ky][kx];
              acc[o][r][1] += wv2 * x4[r + ky][kx + 1];
            }
    }
  }

  // epilogue: bias + relu + float2 store (cols 125..127 are junk, never read)
  const int px = 2 * lane;
#pragma unroll
  for (int o = 0; o < 4; ++o) {
    float b = bias[oc0 + o];
#pragma unroll
    for (int r = 0; r < 2; ++r) {
      float2 v;
      v.x = fmaxf(acc[o][r][0] + b, 0.f);
      v.y = fmaxf(acc[o][r][1] + b, 0.f);
      *(float2*)&fm[(oc0 + o) * FMSTRIDE + (y0 + r) * FMROW + px] = v;
    }
  }
}

// =====================================================================
// K2: fused 1x1 heads + softmax + anchors + decode + clip + keys.
// =====================================================================
__global__ __launch_bounds__(64) void k_heads(const float* __restrict__ fm,
                                              const float* __restrict__ cls_w,
                                              const float* __restrict__ cls_b,
                                              const float* __restrict__ reg_w,
                                              const float* __restrict__ reg_b,
                                              const float* __restrict__ iminfo,
                                              float* __restrict__ out_bbox,
                                              float* __restrict__ out_cls,
                                              float* __restrict__ out_anch,
                                              float* __restrict__ boxes,
                                              uint2* __restrict__ keys) {
  __shared__ float wl[64 * 56];  // [ic64][o54 pad 56]
  const int tid = threadIdx.x;
  const int p = blockIdx.x * 64 + tid;
  const int pc = p < NPOS ? p : NPOS - 1;
  const int py = pc / W_;
  const int px = pc % W_;
  const int pos = py * FMROW + px;

  float acc[56];
#pragma unroll
  for (int o = 0; o < 56; ++o) acc[o] = 0.f;

#pragma unroll 1
  for (int icb = 0; icb < CMID; icb += 64) {
    __syncthreads();
    for (int l = tid; l < 64 * 54; l += 64) {
      int ic = l / 54;
      int o = l % 54;
      float wv = (o < 18) ? cls_w[o * CMID + icb + ic] : reg_w[(o - 18) * CMID + icb + ic];
      wl[ic * 56 + o] = wv;
    }
    __syncthreads();
#pragma unroll 4
    for (int i = 0; i < 64; ++i) {
      float v = fm[(icb + i) * FMSTRIDE + pos];
#pragma unroll
      for (int o4 = 0; o4 < 14; ++o4) {
        float4 w4 = *(const float4*)&wl[i * 56 + o4 * 4];
        acc[o4 * 4 + 0] += w4.x * v;
        acc[o4 * 4 + 1] += w4.y * v;
        acc[o4 * 4 + 2] += w4.z * v;
        acc[o4 * 4 + 3] += w4.w * v;
      }
    }
  }
  if (p >= NPOS) return;

  const float imh = iminfo[0];
  const float imw = iminfo[1];
  const float minsz = 16.0f * iminfo[2];

#pragma unroll
  for (int a = 0; a < 9; ++a) {
    const int n = p * 9 + a;
    float s0 = acc[a * 2 + 0] + cls_b[a * 2 + 0];
    float s1 = acc[a * 2 + 1] + cls_b[a * 2 + 1];
    out_cls[n * 2 + 0] = s0;
    out_cls[n * 2 + 1] = s1;

    float dx = acc[18 + a * 4 + 0] + reg_b[a * 4 + 0];
    float dy = acc[18 + a * 4 + 1] + reg_b[a * 4 + 1];
    float dw = acc[18 + a * 4 + 2] + reg_b[a * 4 + 2];
    float dh = acc[18 + a * 4 + 3] + reg_b[a * 4 + 3];
    out_bbox[n * 4 + 0] = dx;
    out_bbox[n * 4 + 1] = dy;
    out_bbox[n * 4 + 2] = dw;
    out_bbox[n * 4 + 3] = dh;

    float aw = c_aw[a], ah = c_ah[a];
    float cxs = px * 16.0f + 7.5f;
    float cys = py * 16.0f + 7.5f;
    float ax1 = cxs - 0.5f * (aw - 1.0f);
    float ay1 = cys - 0.5f * (ah - 1.0f);
    float ax2 = cxs + 0.5f * (aw - 1.0f);
    float ay2 = cys + 0.5f * (ah - 1.0f);
    out_anch[n * 4 + 0] = ax1;
    out_anch[n * 4 + 1] = ay1;
    out_anch[n * 4 + 2] = ax2;
    out_anch[n * 4 + 3] = ay2;

    float wa = ax2 - ax1 + 1.0f;
    float ha = ay2 - ay1 + 1.0f;
    float cxa = ax1 + 0.5f * wa;
    float cya = ay1 + 0.5f * ha;
    float cx = dx * wa + cxa;
    float cy = dy * ha + cya;
    float ww = wa * expf(dw);
    float hh = ha * expf(dh);
    float bx1 = cx - 0.5f * ww;
    float by1 = cy - 0.5f * hh;
    float bx2 = cx + 0.5f * ww;
    float by2 = cy + 0.5f * hh;
    bx1 = fminf(fmaxf(bx1, 0.f), imw - 1.f);
    by1 = fminf(fmaxf(by1, 0.f), imh - 1.f);
    bx2 = fminf(fmaxf(bx2, 0.f), imw - 1.f);
    by2 = fminf(fmaxf(by2, 0.f), imh - 1.f);
    boxes[n * 4 + 0] = bx1;
    boxes[n * 4 + 1] = by1;
    boxes[n * 4 + 2] = bx2;
    boxes[n * 4 + 3] = by2;

    bool valid = (bx2 - bx1 + 1.0f >= minsz) && (by2 - by1 + 1.0f >= minsz);
    float prob = 1.0f / (1.0f + expf(s0 - s1));
    u32 key = valid ? __float_as_uint(prob) : 0u;
    keys[n] = make_uint2(~key, (u32)n);  // ascending on ~key == descending score, stable
  }
}

// =====================================================================
// K3: single-block select + small sort (two-level histogram threshold,
// stable compaction, 8-pass LSD radix on ~6000 selected).
// =====================================================================
__global__ __launch_bounds__(512) void k_select(const uint2* __restrict__ keys,
                                                uint2* __restrict__ selA,
                                                uint2* __restrict__ selB) {
  __shared__ u32 h[8192];
  __shared__ u32 stot[512];
  __shared__ u32 sB1, sLt1, sB2, sN;
  const int t = threadIdx.x;
  const int s = t * 185;
  const int e = (s + 185 < NA) ? s + 185 : NA;

  // ---- L1 hist: top 12 bits ----
  for (int i = t; i < 4096; i += 512) h[i] = 0;
  __syncthreads();
  for (int i = s; i < e; ++i) atomicAdd(&h[keys[i].x >> 20], 1u);
  __syncthreads();
  {
    u32 loc = 0;
#pragma unroll
    for (int j = 0; j < 8; ++j) loc += h[t * 8 + j];
    stot[t] = loc;
    __syncthreads();
    for (int off = 1; off < 512; off <<= 1) {
      u32 add = (t >= off) ? stot[t - off] : 0u;
      __syncthreads();
      stot[t] += add;
      __syncthreads();
    }
    u32 cb = stot[t] - loc;
    if (cb < PRE && stot[t] >= PRE) {
      u32 run = cb;
#pragma unroll
      for (int j = 0; j < 8; ++j) {
        u32 c = h[t * 8 + j];
        if (run < PRE && run + c >= PRE) { sB1 = t * 8 + j; sLt1 = run; }
        run += c;
      }
    }
  }
  __syncthreads();
  const u32 B1 = sB1;
  const u32 T2 = PRE - sLt1;

  // ---- L2 hist: bits 8..19 within bin B1 ----
  for (int i = t; i < 4096; i += 512) h[i] = 0;
  __syncthreads();
  for (int i = s; i < e; ++i) {
    u32 k = keys[i].x;
    if ((k >> 20) == B1) atomicAdd(&h[(k >> 8) & 0xFFFu], 1u);
  }
  __syncthreads();
  {
    u32 loc = 0;
#pragma unroll
    for (int j = 0; j < 8; ++j) loc += h[t * 8 + j];
    stot[t] = loc;
    __syncthreads();
    for (int off = 1; off < 512; off <<= 1) {
      u32 add = (t >= off) ? stot[t - off] : 0u;
      __syncthreads();
      stot[t] += add;
      __syncthreads();
    }
    u32 cb = stot[t] - loc;
    if (cb < T2 && stot[t] >= T2) {
      u32 run = cb;
#pragma unroll
      for (int j = 0; j < 8; ++j) {
        u32 c = h[t * 8 + j];
        if (run < T2 && run + c >= T2) { sB2 = t * 8 + j; }
        run += c;
      }
    }
  }
  __syncthreads();
  const u32 B2 = sB2;

  // ---- stable compaction ----
  u32 cnt = 0;
  for (int i = s; i < e; ++i) {
    u32 k = keys[i].x;
    u32 hi = k >> 20;
    if (hi < B1 || (hi == B1 && ((k >> 8) & 0xFFFu) <= B2)) cnt++;
  }
  stot[t] = cnt;
  __syncthreads();
  for (int off = 1; off < 512; off <<= 1) {
    u32 add = (t >= off) ? stot[t - off] : 0u;
    __syncthreads();
    stot[t] += add;
    __syncthreads();
  }
  u32 base = stot[t] - cnt;
  if (t == 511) sN = stot[511] < SELCAP ? stot[511] : SELCAP;
  for (int i = s; i < e; ++i) {
    uint2 v = keys[i];
    u32 hi = v.x >> 20;
    if (hi < B1 || (hi == B1 && ((v.x >> 8) & 0xFFFu) <= B2)) {
      if (base < SELCAP) selA[base] = v;
      base++;
    }
  }
  __syncthreads();
  const int n = (int)sN;

  // ---- 8-pass LSD radix on selected set ----
  const int q = (n + 511) / 512;
  const int s2 = t * q;
  const int e2 = (s2 + q < n) ? s2 + q : n;
  uint2* src = selA;
  uint2* dst = selB;
#pragma unroll 1
  for (int pass = 0; pass < 8; ++pass) {
    const int sh = pass * 4;
#pragma unroll
    for (int k = 0; k < 16; ++k) h[k * 512 + t] = 0;
    __syncthreads();
    for (int i = s2; i < e2; ++i) {
      u32 d = (src[i].x >> sh) & 15u;
      h[d * 512 + t] += 1;
    }
    __syncthreads();
    u32 run = 0;
#pragma unroll
    for (int j = 0; j < 16; ++j) {
      u32 v = h[t * 16 + j];
      h[t * 16 + j] = run;
      run += v;
    }
    stot[t] = run;
    __syncthreads();
    for (int off = 1; off < 512; off <<= 1) {
      u32 add = (t >= off) ? stot[t - off] : 0u;
      __syncthreads();
      stot[t] += add;
      __syncthreads();
    }
    u32 cb = (t > 0) ? stot[t - 1] : 0u;
#pragma unroll
    for (int j = 0; j < 16; ++j) h[t * 16 + j] += cb;
    __syncthreads();
    for (int i = s2; i < e2; ++i) {
      uint2 v = src[i];
      u32 d = (v.x >> sh) & 15u;
      u32 off = h[d * 512 + t];
      h[d * 512 + t] = off + 1;
      dst[off] = v;
    }
    __syncthreads();
    uint2* tmp = src;
    src = dst;
    dst = tmp;
  }
}

// =====================================================================
// K4: gather top-6000 props + areas + valid bitset.
// =====================================================================
__global__ __launch_bounds__(256) void k_gather(const uint2* __restrict__ sel,
                                                const float4* __restrict__ boxes,
                                                float4* __restrict__ props,
                                                float* __restrict__ areas,
                                                u64* __restrict__ validw) {
  const int k = blockIdx.x * 256 + threadIdx.x;
  bool valid = false;
  if (k < PRE) {
    uint2 kv = sel[k];
    u32 key = ~kv.x;
    valid = key > 0u;
    float4 b = boxes[kv.y];
    props[k] = b;
    areas[k] = (b.z - b.x + 1.0f) * (b.w - b.y + 1.0f);
  }
  u64 bal = __ballot(valid);
  if ((threadIdx.x & 63) == 0 && k < PRE) validw[k >> 6] = bal;
}

// =====================================================================
// K5: IoU suppression bitmask.
// =====================================================================
__global__ __launch_bounds__(256) void k_iou(const float4* __restrict__ props,
                                             const float* __restrict__ areas,
                                             u64* __restrict__ mask) {
  const int gid = blockIdx.x * 256 + threadIdx.x;
  const int i = gid / 94;
  const int w = gid - i * 94;
  if (i >= PRE) return;
  u64 bits = 0;
  const int j0 = w * 64;
  if (j0 + 63 > i) {
    float4 bi = props[i];
    float ai = areas[i];
    for (int b = 0; b < 64; ++b) {
      int j = j0 + b;
      if (j > i && j < PRE) {
        float4 bj = props[j];
        float iw = fminf(bi.z, bj.z) - fmaxf(bi.x, bj.x) + 1.0f;
        float ih = fminf(bi.w, bj.w) - fmaxf(bi.y, bj.y) + 1.0f;
        iw = fmaxf(iw, 0.f);
        ih = fmaxf(ih, 0.f);
        float inter = iw * ih;
        float aj = areas[j];
        if (inter > 0.7f * (ai + aj - inter)) bits |= (1ull << b);
      }
    }
  }
  mask[(u64)i * 96 + w] = bits;
}

// =====================================================================
// K6: sequential greedy NMS scan (one wave, registers + shfl).
// =====================================================================
__device__ __forceinline__ u64 bcast_u64(u64 v, int src) {
  u32 lo = (u32)v;
  u32 hi = (u32)(v >> 32);
  lo = (u32)__shfl((int)lo, src, 64);
  hi = (u32)__shfl((int)hi, src, 64);
  return ((u64)hi << 32) | (u64)lo;
}

__global__ __launch_bounds__(64) void k_nms(const u64* __restrict__ mask,
                                            const u64* __restrict__ validw,
                                            u64* __restrict__ keepw) {
  const int lane = threadIdx.x;
  const int w0 = (2 * lane < 96) ? 2 * lane : 0;
  const int w1 = (2 * lane < 96) ? 2 * lane + 1 : 1;
  u64 s0 = 0, s1 = 0;
  u64 b0[16], b1[16];
#pragma unroll
  for (int d = 0; d < 16; ++d) {
    b0[d] = mask[(u64)d * 96 + w0];
    b1[d] = mask[(u64)d * 96 + w1];
  }
#pragma unroll 1
  for (int i0 = 0; i0 < PRE; i0 += 16) {
#pragma unroll
    for (int d = 0; d < 16; ++d) {
      int i = i0 + d;
      int w = i >> 6;
      u64 cand = (w & 1) ? s1 : s0;
      u64 word = bcast_u64(cand, w >> 1);
      bool sup = (word >> (i & 63)) & 1ull;
      if (!sup) {
        s0 |= b0[d];
        s1 |= b1[d];
      }
      int ip = i + 16;
      if (ip > PRE - 1) ip = PRE - 1;
      b0[d] = mask[(u64)ip * 96 + w0];
      b1[d] = mask[(u64)ip * 96 + w1];
    }
  }
  if (2 * lane < 94) keepw[2 * lane] = ~s0 & validw[2 * lane];
  if (2 * lane + 1 < 94) keepw[2 * lane + 1] = ~s1 & validw[2 * lane + 1];
}

// =====================================================================
// K7: compact kept boxes in order into rois[300][4], zero-padded.
// =====================================================================
__global__ __launch_bounds__(128) void k_emit(const u64* __restrict__ keepw,
                                              const float4* __restrict__ props,
                                              float* __restrict__ rois) {
  __shared__ u32 base[94];
  const int t = threadIdx.x;
  for (int r = t; r < POST * 4; r += 128) rois[r] = 0.f;
  if (t < 94) base[t] = (u32)__popcll(keepw[t]);
  __syncthreads();
  if (t == 0) {
    u32 run = 0;
    for (int q = 0; q < 94; ++q) {
      u32 c = base[q];
      base[q] = run;
      run += c;
    }
  }
  __syncthreads();
  if (t < 94) {
    u64 kw = keepw[t];
    int rank = (int)base[t];
    while (kw) {
      int b = __ffsll((unsigned long long)kw) - 1;
      kw &= kw - 1;
      if (rank < POST) {
        float4 v = props[t * 64 + b];
        rois[rank * 4 + 0] = v.x;
        rois[rank * 4 + 1] = v.y;
        rois[rank * 4 + 2] = v.z;
        rois[rank * 4 + 3] = v.w;
      }
      rank++;
    }
  }
}

// =====================================================================
extern "C" void kernel_launch(void* const* d_in, const int* in_sizes, int n_in,
                              void* d_out, int out_size, void* d_ws, size_t ws_size,
                              hipStream_t stream) {
  const float* feat   = (const float*)d_in[0];
  const float* iminfo = (const float*)d_in[1];
  const float* conv_w = (const float*)d_in[2];
  const float* conv_b = (const float*)d_in[3];
  const float* cls_w  = (const float*)d_in[4];
  const float* cls_b  = (const float*)d_in[5];
  const float* reg_w  = (const float*)d_in[6];
  const float* reg_b  = (const float*)d_in[7];

  float* out = (float*)d_out;
  float* out_bbox = out;                 // 378000
  float* out_cls  = out + 378000;        // 189000
  float* out_rois = out + 567000;        // 1200
  float* out_anch = out + 568200;        // 378000

  char* ws = (char*)d_ws;
  float* fm      = (float*)(ws + OFF_FM);
  float* boxes   = (float*)(ws + OFF_BOXES);
  uint2* keysA   = (uint2*)(ws + OFF_KEYS);
  uint2* selA    = (uint2*)(ws + OFF_SELA);
  uint2* selB    = (uint2*)(ws + OFF_SELB);
  float4* props  = (float4*)(ws + OFF_PROPS);
  float* areas   = (float*)(ws + OFF_AREAS);
  u64* validw    = (u64*)(ws + OFF_VALIDW);
  u64* mask      = (u64*)(ws + OFF_MASK);
  u64* keepw     = (u64*)(ws + OFF_KEEPW);

  k_conv3<<<dim3(32, 42), 256, 0, stream>>>(feat, conv_w, conv_b, fm);
  k_heads<<<165, 64, 0, stream>>>(fm, cls_w, cls_b, reg_w, reg_b, iminfo,
                                  out_bbox, out_cls, out_anch, boxes, keysA);
  k_select<<<1, 512, 0, stream>>>(keysA, selA, selB);
  k_gather<<<24, 256, 0, stream>>>(selA, (const float4*)boxes, props, areas, validw);
  k_iou<<<2204, 256, 0, stream>>>(props, areas, mask);
  k_nms<<<1, 64, 0, stream>>>(mask, validw, keepw);
  k_emit<<<1, 128, 0, stream>>>(keepw, props, out_rois);
}

// Round 4
// 3056.239 us; speedup vs baseline: 2.1159x; 1.0170x over previous
//
#include <hip/hip_runtime.h>

typedef unsigned int u32;
typedef unsigned long long u64;

#define H_ 84
#define W_ 125
#define CIN 1024
#define CMID 512
#define NPOS 10500           // H_*W_
#define NA 94500             // NPOS*9
#define PRE 6000
#define POST 300
#define FMROW 128
#define FMSTRIDE 10752       // 84*128
#define SELCAP 16384

// base anchor widths/heights (exact)
__constant__ float c_aw[9] = {184.f, 368.f, 736.f, 128.f, 256.f, 512.f, 88.f, 176.f, 352.f};
__constant__ float c_ah[9] = { 96.f, 192.f, 384.f, 128.f, 256.f, 512.f, 176.f, 352.f, 704.f};

// ---------------- workspace layout (bytes) ----------------
#define OFF_FM      0ull            // 512*10752 f32 = 22,020,096
#define OFF_BOXES   22020096ull     // 94500*4 f32   = 1,512,000
#define OFF_KEYS    23532096ull     // 94500 uint2   =   756,000
#define OFF_SELA    24288096ull     // 16384 uint2   =   131,072
#define OFF_SELB    24419168ull     // 16384 uint2   =   131,072
#define OFF_PROPS   24550240ull     // 6000 float4   =    96,000
#define OFF_AREAS   24646240ull     // 6000 f32      =    24,000
#define OFF_VALIDW  24670240ull     // 96 u64        =       768
#define OFF_MASK    24671008ull     // 6000*96 u64   = 4,608,000
#define OFF_KEEPW   29279008ull     // 96 u64        =       768
// total ~29.3 MB

// =====================================================================
// K1: 3x3 conv (1024->512) + bias + ReLU.  fp32, scalar-cache weights.
// Block 256 thr = 4 waves. Wave wv handles oc0 = ocb*16 + wv*4 (4 oc,
// wave-uniform -> weights via s_load into SGPRs, zero LDS/VGPR cost).
// Lane covers out px {2l, 2l+1} across full row width; tile = 16 oc x
// 2 rows x 125 cols. Grid (32 ocb, 42 y) = 1344 blocks. LDS holds only
// the input slab Xs[16ic][4rows][132cols] (33.8 KB), staged linearly
// (conflict-free writes); reads are 8B-aligned float2 (2-way = free).
// =====================================================================
__global__ __launch_bounds__(256, 4) void k_conv3(const float* __restrict__ in,
                                                  const float* __restrict__ w,
                                                  const float* __restrict__ bias,
                                                  float* __restrict__ fm) {
  __shared__ float Xs[16 * 4 * 132];   // 33,792 B
  const int tid = threadIdx.x;
  const int lane = tid & 63;
  const int wvi = __builtin_amdgcn_readfirstlane(tid >> 6);  // 0..3 wave-uniform
  const int ocb = blockIdx.x;          // 0..31
  const int y0 = blockIdx.y * 2;       // 0..82
  const int oc0 = ocb * 16 + wvi * 4;

  float acc[4][2][2];
#pragma unroll
  for (int o = 0; o < 4; ++o)
#pragma unroll
    for (int r = 0; r < 2; ++r) {
      acc[o][r][0] = 0.f;
      acc[o][r][1] = 0.f;
    }

  const int cb = 2 * lane;             // Xs col base (covers cols cb..cb+3)

#pragma unroll 1
  for (int icb = 0; icb < CIN; icb += 16) {
    __syncthreads();
    // stage input: 16 ic x 4 rows x 132 cols, linear writes (no conflicts)
#pragma unroll
    for (int k = 0; k < 33; ++k) {
      int l = tid + k * 256;
      int r132 = l / 132;              // 0..63
      int c = l - r132 * 132;
      int i = r132 >> 2;
      int rr = r132 & 3;
      int yi = y0 - 1 + rr;
      int xi = c - 1;
      float v = 0.f;
      if ((unsigned)yi < 84u && (unsigned)xi < 125u)
        v = in[(icb + i) * (H_ * W_) + yi * W_ + xi];
      Xs[l] = v;
    }
    __syncthreads();

#pragma unroll 2
    for (int i = 0; i < 16; ++i) {
      const int ic = icb + i;
      // wave-uniform weights -> SGPRs (compiler emits s_load)
      float ws[4][9];
#pragma unroll
      for (int o = 0; o < 4; ++o)
#pragma unroll
        for (int e = 0; e < 9; ++e)
          ws[o][e] = w[(oc0 + o) * 9216 + ic * 9 + e];

      // input: 4 rows x 4 cols per lane, two aligned float2 per row
      float x4[4][4];
#pragma unroll
      for (int rr = 0; rr < 4; ++rr) {
        float2 lo = *(const float2*)&Xs[(i * 4 + rr) * 132 + cb];
        float2 hi = *(const float2*)&Xs[(i * 4 + rr) * 132 + cb + 2];
        x4[rr][0] = lo.x;
        x4[rr][1] = lo.y;
        x4[rr][2] = hi.x;
        x4[rr][3] = hi.y;
      }

#pragma unroll
      for (int o = 0; o < 4; ++o)
#pragma unroll
        for (int r = 0; r < 2; ++r)
#pragma unroll
          for (int ky = 0; ky < 3; ++ky)
#pragma unroll
            for (int kx = 0; kx < 3; ++kx) {
              float wv2 = ws[o][ky * 3 + kx];
              acc[o][r][0] += wv2 * x4[r + ky][kx];
              acc[o][r][1] += wv2 * x4[r + ky][kx + 1];
            }
    }
  }

  // epilogue: bias + relu + float2 store (cols 125..127 are junk, never read)
  const int px = 2 * lane;
#pragma unroll
  for (int o = 0; o < 4; ++o) {
    float b = bias[oc0 + o];
#pragma unroll
    for (int r = 0; r < 2; ++r) {
      float2 v;
      v.x = fmaxf(acc[o][r][0] + b, 0.f);
      v.y = fmaxf(acc[o][r][1] + b, 0.f);
      *(float2*)&fm[(oc0 + o) * FMSTRIDE + (y0 + r) * FMROW + px] = v;
    }
  }
}

// =====================================================================
// K2: fused 1x1 heads + softmax + anchors + decode + clip + keys.
// =====================================================================
__global__ __launch_bounds__(64) void k_heads(const float* __restrict__ fm,
                                              const float* __restrict__ cls_w,
                                              const float* __restrict__ cls_b,
                                              const float* __restrict__ reg_w,
                                              const float* __restrict__ reg_b,
                                              const float* __restrict__ iminfo,
                                              float* __restrict__ out_bbox,
                                              float* __restrict__ out_cls,
                                              float* __restrict__ out_anch,
                                              float* __restrict__ boxes,
                                              uint2* __restrict__ keys) {
  __shared__ float wl[64 * 56];  // [ic64][o54 pad 56]
  const int tid = threadIdx.x;
  const int p = blockIdx.x * 64 + tid;
  const int pc = p < NPOS ? p : NPOS - 1;
  const int py = pc / W_;
  const int px = pc % W_;
  const int pos = py * FMROW + px;

  float acc[56];
#pragma unroll
  for (int o = 0; o < 56; ++o) acc[o] = 0.f;

#pragma unroll 1
  for (int icb = 0; icb < CMID; icb += 64) {
    __syncthreads();
    for (int l = tid; l < 64 * 54; l += 64) {
      int ic = l / 54;
      int o = l % 54;
      float wv = (o < 18) ? cls_w[o * CMID + icb + ic] : reg_w[(o - 18) * CMID + icb + ic];
      wl[ic * 56 + o] = wv;
    }
    __syncthreads();
#pragma unroll 4
    for (int i = 0; i < 64; ++i) {
      float v = fm[(icb + i) * FMSTRIDE + pos];
#pragma unroll
      for (int o4 = 0; o4 < 14; ++o4) {
        float4 w4 = *(const float4*)&wl[i * 56 + o4 * 4];
        acc[o4 * 4 + 0] += w4.x * v;
        acc[o4 * 4 + 1] += w4.y * v;
        acc[o4 * 4 + 2] += w4.z * v;
        acc[o4 * 4 + 3] += w4.w * v;
      }
    }
  }
  if (p >= NPOS) return;

  const float imh = iminfo[0];
  const float imw = iminfo[1];
  const float minsz = 16.0f * iminfo[2];

#pragma unroll
  for (int a = 0; a < 9; ++a) {
    const int n = p * 9 + a;
    float s0 = acc[a * 2 + 0] + cls_b[a * 2 + 0];
    float s1 = acc[a * 2 + 1] + cls_b[a * 2 + 1];
    out_cls[n * 2 + 0] = s0;
    out_cls[n * 2 + 1] = s1;

    float dx = acc[18 + a * 4 + 0] + reg_b[a * 4 + 0];
    float dy = acc[18 + a * 4 + 1] + reg_b[a * 4 + 1];
    float dw = acc[18 + a * 4 + 2] + reg_b[a * 4 + 2];
    float dh = acc[18 + a * 4 + 3] + reg_b[a * 4 + 3];
    out_bbox[n * 4 + 0] = dx;
    out_bbox[n * 4 + 1] = dy;
    out_bbox[n * 4 + 2] = dw;
    out_bbox[n * 4 + 3] = dh;

    float aw = c_aw[a], ah = c_ah[a];
    float cxs = px * 16.0f + 7.5f;
    float cys = py * 16.0f + 7.5f;
    float ax1 = cxs - 0.5f * (aw - 1.0f);
    float ay1 = cys - 0.5f * (ah - 1.0f);
    float ax2 = cxs + 0.5f * (aw - 1.0f);
    float ay2 = cys + 0.5f * (ah - 1.0f);
    out_anch[n * 4 + 0] = ax1;
    out_anch[n * 4 + 1] = ay1;
    out_anch[n * 4 + 2] = ax2;
    out_anch[n * 4 + 3] = ay2;

    float wa = ax2 - ax1 + 1.0f;
    float ha = ay2 - ay1 + 1.0f;
    float cxa = ax1 + 0.5f * wa;
    float cya = ay1 + 0.5f * ha;
    float cx = dx * wa + cxa;
    float cy = dy * ha + cya;
    float ww = wa * expf(dw);
    float hh = ha * expf(dh);
    float bx1 = cx - 0.5f * ww;
    float by1 = cy - 0.5f * hh;
    float bx2 = cx + 0.5f * ww;
    float by2 = cy + 0.5f * hh;
    bx1 = fminf(fmaxf(bx1, 0.f), imw - 1.f);
    by1 = fminf(fmaxf(by1, 0.f), imh - 1.f);
    bx2 = fminf(fmaxf(bx2, 0.f), imw - 1.f);
    by2 = fminf(fmaxf(by2, 0.f), imh - 1.f);
    boxes[n * 4 + 0] = bx1;
    boxes[n * 4 + 1] = by1;
    boxes[n * 4 + 2] = bx2;
    boxes[n * 4 + 3] = by2;

    bool valid = (bx2 - bx1 + 1.0f >= minsz) && (by2 - by1 + 1.0f >= minsz);
    float prob = 1.0f / (1.0f + expf(s0 - s1));
    u32 key = valid ? __float_as_uint(prob) : 0u;
    keys[n] = make_uint2(~key, (u32)n);  // ascending on ~key == descending score, stable
  }
}

// =====================================================================
// K3: single-block select + small sort (two-level histogram threshold,
// stable compaction, 8-pass LSD radix on ~6000 selected).
// =====================================================================
__global__ __launch_bounds__(512) void k_select(const uint2* __restrict__ keys,
                                                uint2* __restrict__ selA,
                                                uint2* __restrict__ selB) {
  __shared__ u32 h[8192];
  __shared__ u32 stot[512];
  __shared__ u32 sB1, sLt1, sB2, sN;
  const int t = threadIdx.x;
  const int s = t * 185;
  const int e = (s + 185 < NA) ? s + 185 : NA;

  // ---- L1 hist: top 12 bits ----
  for (int i = t; i < 4096; i += 512) h[i] = 0;
  __syncthreads();
  for (int i = s; i < e; ++i) atomicAdd(&h[keys[i].x >> 20], 1u);
  __syncthreads();
  {
    u32 loc = 0;
#pragma unroll
    for (int j = 0; j < 8; ++j) loc += h[t * 8 + j];
    stot[t] = loc;
    __syncthreads();
    for (int off = 1; off < 512; off <<= 1) {
      u32 add = (t >= off) ? stot[t - off] : 0u;
      __syncthreads();
      stot[t] += add;
      __syncthreads();
    }
    u32 cb = stot[t] - loc;
    if (cb < PRE && stot[t] >= PRE) {
      u32 run = cb;
#pragma unroll
      for (int j = 0; j < 8; ++j) {
        u32 c = h[t * 8 + j];
        if (run < PRE && run + c >= PRE) { sB1 = t * 8 + j; sLt1 = run; }
        run += c;
      }
    }
  }
  __syncthreads();
  const u32 B1 = sB1;
  const u32 T2 = PRE - sLt1;

  // ---- L2 hist: bits 8..19 within bin B1 ----
  for (int i = t; i < 4096; i += 512) h[i] = 0;
  __syncthreads();
  for (int i = s; i < e; ++i) {
    u32 k = keys[i].x;
    if ((k >> 20) == B1) atomicAdd(&h[(k >> 8) & 0xFFFu], 1u);
  }
  __syncthreads();
  {
    u32 loc = 0;
#pragma unroll
    for (int j = 0; j < 8; ++j) loc += h[t * 8 + j];
    stot[t] = loc;
    __syncthreads();
    for (int off = 1; off < 512; off <<= 1) {
      u32 add = (t >= off) ? stot[t - off] : 0u;
      __syncthreads();
      stot[t] += add;
      __syncthreads();
    }
    u32 cb = stot[t] - loc;
    if (cb < T2 && stot[t] >= T2) {
      u32 run = cb;
#pragma unroll
      for (int j = 0; j < 8; ++j) {
        u32 c = h[t * 8 + j];
        if (run < T2 && run + c >= T2) { sB2 = t * 8 + j; }
        run += c;
      }
    }
  }
  __syncthreads();
  const u32 B2 = sB2;

  // ---- stable compaction ----
  u32 cnt = 0;
  for (int i = s; i < e; ++i) {
    u32 k = keys[i].x;
    u32 hi = k >> 20;
    if (hi < B1 || (hi == B1 && ((k >> 8) & 0xFFFu) <= B2)) cnt++;
  }
  stot[t] = cnt;
  __syncthreads();
  for (int off = 1; off < 512; off <<= 1) {
    u32 add = (t >= off) ? stot[t - off] : 0u;
    __syncthreads();
    stot[t] += add;
    __syncthreads();
  }
  u32 base = stot[t] - cnt;
  if (t == 511) sN = stot[511] < SELCAP ? stot[511] : SELCAP;
  for (int i = s; i < e; ++i) {
    uint2 v = keys[i];
    u32 hi = v.x >> 20;
    if (hi < B1 || (hi == B1 && ((v.x >> 8) & 0xFFFu) <= B2)) {
      if (base < SELCAP) selA[base] = v;
      base++;
    }
  }
  __syncthreads();
  const int n = (int)sN;

  // ---- 8-pass LSD radix on selected set ----
  const int q = (n + 511) / 512;
  const int s2 = t * q;
  const int e2 = (s2 + q < n) ? s2 + q : n;
  uint2* src = selA;
  uint2* dst = selB;
#pragma unroll 1
  for (int pass = 0; pass < 8; ++pass) {
    const int sh = pass * 4;
#pragma unroll
    for (int k = 0; k < 16; ++k) h[k * 512 + t] = 0;
    __syncthreads();
    for (int i = s2; i < e2; ++i) {
      u32 d = (src[i].x >> sh) & 15u;
      h[d * 512 + t] += 1;
    }
    __syncthreads();
    u32 run = 0;
#pragma unroll
    for (int j = 0; j < 16; ++j) {
      u32 v = h[t * 16 + j];
      h[t * 16 + j] = run;
      run += v;
    }
    stot[t] = run;
    __syncthreads();
    for (int off = 1; off < 512; off <<= 1) {
      u32 add = (t >= off) ? stot[t - off] : 0u;
      __syncthreads();
      stot[t] += add;
      __syncthreads();
    }
    u32 cb = (t > 0) ? stot[t - 1] : 0u;
#pragma unroll
    for (int j = 0; j < 16; ++j) h[t * 16 + j] += cb;
    __syncthreads();
    for (int i = s2; i < e2; ++i) {
      uint2 v = src[i];
      u32 d = (v.x >> sh) & 15u;
      u32 off = h[d * 512 + t];
      h[d * 512 + t] = off + 1;
      dst[off] = v;
    }
    __syncthreads();
    uint2* tmp = src;
    src = dst;
    dst = tmp;
  }
}

// =====================================================================
// K4: gather top-6000 props + areas + valid bitset.
// =====================================================================
__global__ __launch_bounds__(256) void k_gather(const uint2* __restrict__ sel,
                                                const float4* __restrict__ boxes,
                                                float4* __restrict__ props,
                                                float* __restrict__ areas,
                                                u64* __restrict__ validw) {
  const int k = blockIdx.x * 256 + threadIdx.x;
  bool valid = false;
  if (k < PRE) {
    uint2 kv = sel[k];
    u32 key = ~kv.x;
    valid = key > 0u;
    float4 b = boxes[kv.y];
    props[k] = b;
    areas[k] = (b.z - b.x + 1.0f) * (b.w - b.y + 1.0f);
  }
  u64 bal = __ballot(valid);
  if ((threadIdx.x & 63) == 0 && k < PRE) validw[k >> 6] = bal;
}

// =====================================================================
// K5: IoU suppression bitmask.
// =====================================================================
__global__ __launch_bounds__(256) void k_iou(const float4* __restrict__ props,
                                             const float* __restrict__ areas,
                                             u64* __restrict__ mask) {
  const int gid = blockIdx.x * 256 + threadIdx.x;
  const int i = gid / 94;
  const int w = gid - i * 94;
  if (i >= PRE) return;
  u64 bits = 0;
  const int j0 = w * 64;
  if (j0 + 63 > i) {
    float4 bi = props[i];
    float ai = areas[i];
    for (int b = 0; b < 64; ++b) {
      int j = j0 + b;
      if (j > i && j < PRE) {
        float4 bj = props[j];
        float iw = fminf(bi.z, bj.z) - fmaxf(bi.x, bj.x) + 1.0f;
        float ih = fminf(bi.w, bj.w) - fmaxf(bi.y, bj.y) + 1.0f;
        iw = fmaxf(iw, 0.f);
        ih = fmaxf(ih, 0.f);
        float inter = iw * ih;
        float aj = areas[j];
        if (inter > 0.7f * (ai + aj - inter)) bits |= (1ull << b);
      }
    }
  }
  mask[(u64)i * 96 + w] = bits;
}

// =====================================================================
// K6: sequential greedy NMS scan (one wave, registers + shfl).
// =====================================================================
__device__ __forceinline__ u64 bcast_u64(u64 v, int src) {
  u32 lo = (u32)v;
  u32 hi = (u32)(v >> 32);
  lo = (u32)__shfl((int)lo, src, 64);
  hi = (u32)__shfl((int)hi, src, 64);
  return ((u64)hi << 32) | (u64)lo;
}

__global__ __launch_bounds__(64) void k_nms(const u64* __restrict__ mask,
                                            const u64* __restrict__ validw,
                                            u64* __restrict__ keepw) {
  const int lane = threadIdx.x;
  const int w0 = (2 * lane < 96) ? 2 * lane : 0;
  const int w1 = (2 * lane < 96) ? 2 * lane + 1 : 1;
  u64 s0 = 0, s1 = 0;
  u64 b0[16], b1[16];
#pragma unroll
  for (int d = 0; d < 16; ++d) {
    b0[d] = mask[(u64)d * 96 + w0];
    b1[d] = mask[(u64)d * 96 + w1];
  }
#pragma unroll 1
  for (int i0 = 0; i0 < PRE; i0 += 16) {
#pragma unroll
    for (int d = 0; d < 16; ++d) {
      int i = i0 + d;
      int w = i >> 6;
      u64 cand = (w & 1) ? s1 : s0;
      u64 word = bcast_u64(cand, w >> 1);
      bool sup = (word >> (i & 63)) & 1ull;
      if (!sup) {
        s0 |= b0[d];
        s1 |= b1[d];
      }
      int ip = i + 16;
      if (ip > PRE - 1) ip = PRE - 1;
      b0[d] = mask[(u64)ip * 96 + w0];
      b1[d] = mask[(u64)ip * 96 + w1];
    }
  }
  if (2 * lane < 94) keepw[2 * lane] = ~s0 & validw[2 * lane];
  if (2 * lane + 1 < 94) keepw[2 * lane + 1] = ~s1 & validw[2 * lane + 1];
}

// =====================================================================
// K7: compact kept boxes in order into rois[300][4], zero-padded.
// =====================================================================
__global__ __launch_bounds__(128) void k_emit(const u64* __restrict__ keepw,
                                              const float4* __restrict__ props,
                                              float* __restrict__ rois) {
  __shared__ u32 base[94];
  const int t = threadIdx.x;
  for (int r = t; r < POST * 4; r += 128) rois[r] = 0.f;
  if (t < 94) base[t] = (u32)__popcll(keepw[t]);
  __syncthreads();
  if (t == 0) {
    u32 run = 0;
    for (int q = 0; q < 94; ++q) {
      u32 c = base[q];
      base[q] = run;
      run += c;
    }
  }
  __syncthreads();
  if (t < 94) {
    u64 kw = keepw[t];
    int rank = (int)base[t];
    while (kw) {
      int b = __ffsll((unsigned long long)kw) - 1;
      kw &= kw - 1;
      if (rank < POST) {
        float4 v = props[t * 64 + b];
        rois[rank * 4 + 0] = v.x;
        rois[rank * 4 + 1] = v.y;
        rois[rank * 4 + 2] = v.z;
        rois[rank * 4 + 3] = v.w;
      }
      rank++;
    }
  }
}

// =====================================================================
extern "C" void kernel_launch(void* const* d_in, const int* in_sizes, int n_in,
                              void* d_out, int out_size, void* d_ws, size_t ws_size,
                              hipStream_t stream) {
  const float* feat   = (const float*)d_in[0];
  const float* iminfo = (const float*)d_in[1];
  const float* conv_w = (const float*)d_in[2];
  const float* conv_b = (const float*)d_in[3];
  const float* cls_w  = (const float*)d_in[4];
  const float* cls_b  = (const float*)d_in[5];
  const float* reg_w  = (const float*)d_in[6];
  const float* reg_b  = (const float*)d_in[7];

  float* out = (float*)d_out;
  float* out_bbox = out;                 // 378000
  float* out_cls  = out + 378000;        // 189000
  float* out_rois = out + 567000;        // 1200
  float* out_anch = out + 568200;        // 378000

  char* ws = (char*)d_ws;
  float* fm      = (float*)(ws + OFF_FM);
  float* boxes   = (float*)(ws + OFF_BOXES);
  uint2* keysA   = (uint2*)(ws + OFF_KEYS);
  uint2* selA    = (uint2*)(ws + OFF_SELA);
  uint2* selB    = (uint2*)(ws + OFF_SELB);
  float4* props  = (float4*)(ws + OFF_PROPS);
  float* areas   = (float*)(ws + OFF_AREAS);
  u64* validw    = (u64*)(ws + OFF_VALIDW);
  u64* mask      = (u64*)(ws + OFF_MASK);
  u64* keepw     = (u64*)(ws + OFF_KEEPW);

  k_conv3<<<dim3(32, 42), 256, 0, stream>>>(feat, conv_w, conv_b, fm);
  k_heads<<<165, 64, 0, stream>>>(fm, cls_w, cls_b, reg_w, reg_b, iminfo,
                                  out_bbox, out_cls, out_anch, boxes, keysA);
  k_select<<<1, 512, 0, stream>>>(keysA, selA, selB);
  k_gather<<<24, 256, 0, stream>>>(selA, (const float4*)boxes, props, areas, validw);
  k_iou<<<2204, 256, 0, stream>>>(props, areas, mask);
  k_nms<<<1, 64, 0, stream>>>(mask, validw, keepw);
  k_emit<<<1, 128, 0, stream>>>(keepw, props, out_rois);
}